// Round 2
// baseline (1037.864 us; speedup 1.0000x reference)
//
#include <hip/hip_runtime.h>
#include <math.h>

// GraphSAGE 3-layer forward, fp32, MI355X.
// CSR build (deg -> shfl-scan -> fill), per layer {mean-agg, fused GEMM
// [h|hn]@[Ws;Wn]+b (+ReLU)}, final log_softmax over 64 classes.

// ---------------- CSR build ----------------

__global__ __launch_bounds__(256) void count_deg_kernel(const int* __restrict__ dst,
                                                        int* __restrict__ deg, int E) {
  int e = blockIdx.x * blockDim.x + threadIdx.x;
  if (e < E) atomicAdd(&deg[dst[e]], 1);
}

// single-block scan, wave-shfl based (4 barriers per 1024-chunk)
__global__ __launch_bounds__(1024) void scan_kernel(const int* __restrict__ deg,
                                                    int* __restrict__ rowptr, int N) {
  __shared__ int wsum[16];
  __shared__ int soff;
  int tid = threadIdx.x;
  int lane = tid & 63;
  int wave = tid >> 6;
  if (tid == 0) soff = 0;
  __syncthreads();
  for (int base = 0; base < N; base += 1024) {
    int i = base + tid;
    int v = (i < N) ? deg[i] : 0;
    // inclusive wave scan
    int x = v;
#pragma unroll
    for (int d = 1; d < 64; d <<= 1) {
      int t = __shfl_up(x, d, 64);
      if (lane >= d) x += t;
    }
    if (lane == 63) wsum[wave] = x;
    __syncthreads();
    if (wave == 0) {
      int w = (lane < 16) ? wsum[lane] : 0;
#pragma unroll
      for (int d = 1; d < 16; d <<= 1) {
        int t = __shfl_up(w, d, 64);
        if (lane >= d) w += t;
      }
      if (lane < 16) wsum[lane] = w;  // inclusive over wave sums
    }
    __syncthreads();
    int waveoff = (wave == 0) ? 0 : wsum[wave - 1];
    if (i < N) rowptr[i] = soff + waveoff + x - v;  // exclusive prefix
    __syncthreads();                                // all reads of soff done
    if (tid == 0) soff += wsum[15];
    __syncthreads();
  }
  if (tid == 0) rowptr[N] = soff;
}

__global__ __launch_bounds__(256) void fill_kernel(const int* __restrict__ src,
                                                   const int* __restrict__ dst,
                                                   const int* __restrict__ rowptr,
                                                   int* __restrict__ cursor,
                                                   int* __restrict__ esrc, int E) {
  int e = blockIdx.x * blockDim.x + threadIdx.x;
  if (e < E) {
    int d = dst[e];
    int pos = atomicAdd(&cursor[d], 1);
    esrc[rowptr[d] + pos] = src[e];
  }
}

// ---------------- mean aggregation ----------------
// one wave per node; lane owns float4 chunk (64 lanes * 4 floats = 256)

__global__ __launch_bounds__(256) void agg_kernel(const float* __restrict__ h,
                                                  const int* __restrict__ rowptr,
                                                  const int* __restrict__ esrc,
                                                  float* __restrict__ out, int N) {
  int gid = blockIdx.x * blockDim.x + threadIdx.x;
  int node = gid >> 6;
  int lane = gid & 63;
  if (node >= N) return;
  int start = rowptr[node], end = rowptr[node + 1];
  const float* hb = h + (size_t)lane * 4;
  float4 acc = make_float4(0.f, 0.f, 0.f, 0.f);
  int e = start;
  for (; e + 4 <= end; e += 4) {
    int s0 = esrc[e + 0], s1 = esrc[e + 1], s2 = esrc[e + 2], s3 = esrc[e + 3];
    float4 v0 = *(const float4*)(hb + (size_t)s0 * 256);
    float4 v1 = *(const float4*)(hb + (size_t)s1 * 256);
    float4 v2 = *(const float4*)(hb + (size_t)s2 * 256);
    float4 v3 = *(const float4*)(hb + (size_t)s3 * 256);
    acc.x += (v0.x + v1.x) + (v2.x + v3.x);
    acc.y += (v0.y + v1.y) + (v2.y + v3.y);
    acc.z += (v0.z + v1.z) + (v2.z + v3.z);
    acc.w += (v0.w + v1.w) + (v2.w + v3.w);
  }
  for (; e < end; ++e) {
    int s = esrc[e];
    float4 v = *(const float4*)(hb + (size_t)s * 256);
    acc.x += v.x; acc.y += v.y; acc.z += v.z; acc.w += v.w;
  }
  float inv = 1.0f / fmaxf((float)(end - start), 1.0f);
  acc.x *= inv; acc.y *= inv; acc.z *= inv; acc.w *= inv;
  *(float4*)(out + (size_t)node * 256 + lane * 4) = acc;
}

// ---------------- fused GEMM 128x128: out = A1@W1 + A2@W2 + b ----------------
// A1,A2: [M,256] row-major. W1,W2: [256,Nout] row-major (Nout multiple of 128).
// BM=128, BN=128, BK=16, 256 threads, 8x8 micro-tile per thread.

template <int RELU>
__global__ __launch_bounds__(256) void gemm128_kernel(const float* __restrict__ A1,
                                                      const float* __restrict__ A2,
                                                      const float* __restrict__ W1,
                                                      const float* __restrict__ W2,
                                                      const float* __restrict__ bias,
                                                      float* __restrict__ out,
                                                      int M, int Nout) {
  const int BM = 128, BK = 16;
  __shared__ float As[BK][BM + 4];  // stride 132 words = 528B (16B-aligned rows)
  __shared__ float Bs[BK][128];
  int tid = threadIdx.x;
  int tx = tid & 15;   // col group: cols tx*8 .. +7
  int ty = tid >> 4;   // row group: rows ty*8 .. +7
  int r0 = blockIdx.x * BM;
  int c0 = blockIdx.y * 128;

  float acc[8][8] = {};

  for (int kt = 0; kt < 32; ++kt) {          // K = 512 total (two 256 halves)
    const float* Ap = (kt < 16) ? A1 : A2;
    const float* Wp = (kt < 16) ? W1 : W2;
    int kh = (kt & 15) * BK;

    // A tile: 128 rows x 16 k = 512 float4, 2/thread; store transposed
#pragma unroll
    for (int i = 0; i < 2; ++i) {
      int f = tid + i * 256;
      int row = f >> 2;   // 0..127
      int c4 = f & 3;     // 0..3
      int gr = r0 + row;
      if (gr >= M) gr = M - 1;  // clamped read; stores are guarded
      float4 v = *(const float4*)(Ap + (size_t)gr * 256 + kh + c4 * 4);
      As[c4 * 4 + 0][row] = v.x;
      As[c4 * 4 + 1][row] = v.y;
      As[c4 * 4 + 2][row] = v.z;
      As[c4 * 4 + 3][row] = v.w;
    }
    // B tile: 16 k x 128 cols = 512 float4, 2/thread
#pragma unroll
    for (int i = 0; i < 2; ++i) {
      int f = tid + i * 256;
      int row = f >> 5;   // 0..15
      int c4 = f & 31;    // 0..31
      float4 v = *(const float4*)(Wp + (size_t)(kh + row) * Nout + c0 + c4 * 4);
      *(float4*)&Bs[row][c4 * 4] = v;
    }
    __syncthreads();

#pragma unroll
    for (int kk = 0; kk < BK; ++kk) {
      float a[8], b[8];
      *(float4*)&a[0] = *(const float4*)&As[kk][ty * 8];
      *(float4*)&a[4] = *(const float4*)&As[kk][ty * 8 + 4];
      *(float4*)&b[0] = *(const float4*)&Bs[kk][tx * 8];
      *(float4*)&b[4] = *(const float4*)&Bs[kk][tx * 8 + 4];
#pragma unroll
      for (int i = 0; i < 8; ++i)
#pragma unroll
        for (int j = 0; j < 8; ++j) acc[i][j] += a[i] * b[j];
    }
    __syncthreads();
  }

#pragma unroll
  for (int i = 0; i < 8; ++i) {
    int gr = r0 + ty * 8 + i;
    if (gr < M) {
#pragma unroll
      for (int g = 0; g < 2; ++g) {
        int cc = c0 + tx * 8 + g * 4;
        float4 v;
        v.x = acc[i][g * 4 + 0] + bias[cc + 0];
        v.y = acc[i][g * 4 + 1] + bias[cc + 1];
        v.z = acc[i][g * 4 + 2] + bias[cc + 2];
        v.w = acc[i][g * 4 + 3] + bias[cc + 3];
        if (RELU) {
          v.x = fmaxf(v.x, 0.f); v.y = fmaxf(v.y, 0.f);
          v.z = fmaxf(v.z, 0.f); v.w = fmaxf(v.w, 0.f);
        }
        *(float4*)(out + (size_t)gr * Nout + cc) = v;
      }
    }
  }
}

// ---------------- fused GEMM 64x64 (layer 2, Nout=64) ----------------

template <int RELU>
__global__ __launch_bounds__(256) void gemm64_kernel(const float* __restrict__ A1,
                                                     const float* __restrict__ A2,
                                                     const float* __restrict__ W1,
                                                     const float* __restrict__ W2,
                                                     const float* __restrict__ bias,
                                                     float* __restrict__ out,
                                                     int M, int Nout) {
  const int BM = 64, BN = 64, BK = 32;
  __shared__ float As[BK][BM + 4];
  __shared__ float Bs[BK][BN];
  int tid = threadIdx.x;
  int tx = tid & 15;
  int ty = tid >> 4;
  int r0 = blockIdx.x * BM;
  int c0 = blockIdx.y * BN;

  float acc[4][4] = {};

  for (int kt = 0; kt < 16; ++kt) {
    const float* Ap = (kt < 8) ? A1 : A2;
    const float* Wp = (kt < 8) ? W1 : W2;
    int kh = (kt & 7) * BK;

#pragma unroll
    for (int i = 0; i < 2; ++i) {
      int f = tid + i * 256;
      int row = f >> 3;
      int c4 = f & 7;
      int gr = r0 + row;
      if (gr >= M) gr = M - 1;
      float4 v = *(const float4*)(Ap + (size_t)gr * 256 + kh + c4 * 4);
      As[c4 * 4 + 0][row] = v.x;
      As[c4 * 4 + 1][row] = v.y;
      As[c4 * 4 + 2][row] = v.z;
      As[c4 * 4 + 3][row] = v.w;
    }
#pragma unroll
    for (int i = 0; i < 2; ++i) {
      int f = tid + i * 256;
      int row = f >> 4;
      int c4 = f & 15;
      float4 v = *(const float4*)(Wp + (size_t)(kh + row) * Nout + c0 + c4 * 4);
      *(float4*)&Bs[row][c4 * 4] = v;
    }
    __syncthreads();

#pragma unroll
    for (int kk = 0; kk < BK; ++kk) {
      float a[4], b[4];
      *(float4*)a = *(const float4*)&As[kk][ty * 4];
      *(float4*)b = *(const float4*)&Bs[kk][tx * 4];
#pragma unroll
      for (int i = 0; i < 4; ++i)
#pragma unroll
        for (int j = 0; j < 4; ++j) acc[i][j] += a[i] * b[j];
    }
    __syncthreads();
  }

#pragma unroll
  for (int i = 0; i < 4; ++i) {
    int gr = r0 + ty * 4 + i;
    if (gr < M) {
      float4 v;
      v.x = acc[i][0] + bias[c0 + tx * 4 + 0];
      v.y = acc[i][1] + bias[c0 + tx * 4 + 1];
      v.z = acc[i][2] + bias[c0 + tx * 4 + 2];
      v.w = acc[i][3] + bias[c0 + tx * 4 + 3];
      if (RELU) {
        v.x = fmaxf(v.x, 0.f); v.y = fmaxf(v.y, 0.f);
        v.z = fmaxf(v.z, 0.f); v.w = fmaxf(v.w, 0.f);
      }
      *(float4*)(out + (size_t)gr * Nout + c0 + tx * 4) = v;
    }
  }
}

// ---------------- log_softmax over 64 classes ----------------

__global__ __launch_bounds__(256) void logsoftmax_kernel(float* __restrict__ out, int N) {
  int gid = blockIdx.x * blockDim.x + threadIdx.x;
  int node = gid >> 6;
  int lane = gid & 63;
  if (node >= N) return;
  size_t idx = (size_t)node * 64 + lane;
  float v = out[idx];
  float m = v;
  for (int o = 32; o > 0; o >>= 1) m = fmaxf(m, __shfl_xor(m, o, 64));
  float ex = expf(v - m);
  float s = ex;
  for (int o = 32; o > 0; o >>= 1) s += __shfl_xor(s, o, 64);
  out[idx] = v - m - logf(s);
}

// ---------------- launch ----------------

extern "C" void kernel_launch(void* const* d_in, const int* in_sizes, int n_in,
                              void* d_out, int out_size, void* d_ws, size_t ws_size,
                              hipStream_t stream) {
  const float* features = (const float*)d_in[0];
  const int* src = (const int*)d_in[1];
  const int* dst = (const int*)d_in[2];
  const float* Ws0 = (const float*)d_in[3];
  const float* Wn0 = (const float*)d_in[4];
  const float* b0  = (const float*)d_in[5];
  const float* Ws1 = (const float*)d_in[6];
  const float* Wn1 = (const float*)d_in[7];
  const float* b1  = (const float*)d_in[8];
  const float* Ws2 = (const float*)d_in[9];
  const float* Wn2 = (const float*)d_in[10];
  const float* b2  = (const float*)d_in[11];
  float* out = (float*)d_out;

  const int N = in_sizes[0] / 256;  // 50000
  const int E = in_sizes[1];        // 800000

  char* ws = (char*)d_ws;
  size_t off = 0;
  auto alloc = [&](size_t bytes) -> void* {
    void* p = ws + off;
    off += (bytes + 255) & ~(size_t)255;
    return p;
  };
  float* hn   = (float*)alloc((size_t)N * 256 * 4);
  float* h1   = (float*)alloc((size_t)N * 256 * 4);
  float* h2   = (float*)alloc((size_t)N * 256 * 4);
  int* rowptr = (int*)alloc((size_t)(N + 1) * 4);
  int* deg    = (int*)alloc((size_t)N * 4);
  int* cursor = (int*)alloc((size_t)N * 4);
  int* esrc   = (int*)alloc((size_t)E * 4);
  (void)ws_size;

  hipMemsetAsync(deg, 0, (size_t)N * 4, stream);
  hipMemsetAsync(cursor, 0, (size_t)N * 4, stream);

  int eBlocks = (E + 255) / 256;
  count_deg_kernel<<<eBlocks, 256, 0, stream>>>(dst, deg, E);
  scan_kernel<<<1, 1024, 0, stream>>>(deg, rowptr, N);
  fill_kernel<<<eBlocks, 256, 0, stream>>>(src, dst, rowptr, cursor, esrc, E);

  int aggBlocks = ((size_t)N * 64 + 255) / 256;  // one wave per node
  dim3 g128((N + 127) / 128, 2);                 // Nout=256
  dim3 g64((N + 63) / 64, 1);                    // Nout=64

  // layer 0
  agg_kernel<<<aggBlocks, 256, 0, stream>>>(features, rowptr, esrc, hn, N);
  gemm128_kernel<1><<<g128, 256, 0, stream>>>(features, hn, Ws0, Wn0, b0, h1, N, 256);
  // layer 1
  agg_kernel<<<aggBlocks, 256, 0, stream>>>(h1, rowptr, esrc, hn, N);
  gemm128_kernel<1><<<g128, 256, 0, stream>>>(h1, hn, Ws1, Wn1, b1, h2, N, 256);
  // layer 2
  agg_kernel<<<aggBlocks, 256, 0, stream>>>(h2, rowptr, esrc, hn, N);
  gemm64_kernel<0><<<g64, 256, 0, stream>>>(h2, hn, Ws2, Wn2, b2, out, N, 64);
  // log_softmax in-place on d_out
  logsoftmax_kernel<<<aggBlocks, 256, 0, stream>>>(out, N);
}

// Round 7
// 736.538 us; speedup vs baseline: 1.4091x; 1.4091x over previous
//
#include <hip/hip_runtime.h>
#include <math.h>

// GraphSAGE 3-layer forward, MI355X. Split-bf16 (hi+lo) MFMA GEMMs with fp32
// accumulate (~fp32 accuracy), fp32 aggregation, CSR gather-sum.
// h tensors live as {hi,lo} bf16 plane pairs; weights pre-transposed/split.

typedef __attribute__((ext_vector_type(8))) short short8;
typedef __attribute__((ext_vector_type(4))) float f32x4;

__device__ __forceinline__ unsigned short f2bf(float x) {
  union { float f; unsigned int u; } c; c.f = x;
  unsigned int r = c.u + 0x7FFFu + ((c.u >> 16) & 1u);  // RNE
  return (unsigned short)(r >> 16);
}
__device__ __forceinline__ float bf2f(unsigned short h) {
  union { unsigned int u; float f; } c; c.u = ((unsigned int)h) << 16;
  return c.f;
}
__device__ __forceinline__ void gload16(const void* g, void* l) {
  void* gg = const_cast<void*>(g);
  __builtin_amdgcn_global_load_lds((__attribute__((address_space(1))) void*)gg,
                                   (__attribute__((address_space(3))) void*)l, 16, 0, 0);
}

// ---------------- CSR build ----------------

__global__ __launch_bounds__(256) void count_deg_kernel(const int* __restrict__ dst,
                                                        int* __restrict__ deg, int E) {
  int e = blockIdx.x * blockDim.x + threadIdx.x;
  if (e < E) atomicAdd(&deg[dst[e]], 1);
}

__global__ __launch_bounds__(1024) void scan_kernel(const int* __restrict__ deg,
                                                    int* __restrict__ rowptr, int N) {
  __shared__ int wsum[16];
  __shared__ int soff;
  int tid = threadIdx.x;
  int lane = tid & 63;
  int wave = tid >> 6;
  if (tid == 0) soff = 0;
  __syncthreads();
  for (int base = 0; base < N; base += 1024) {
    int i = base + tid;
    int v = (i < N) ? deg[i] : 0;
    int x = v;
#pragma unroll
    for (int d = 1; d < 64; d <<= 1) {
      int t = __shfl_up(x, d, 64);
      if (lane >= d) x += t;
    }
    if (lane == 63) wsum[wave] = x;
    __syncthreads();
    if (wave == 0) {
      int w = (lane < 16) ? wsum[lane] : 0;
#pragma unroll
      for (int d = 1; d < 16; d <<= 1) {
        int t = __shfl_up(w, d, 64);
        if (lane >= d) w += t;
      }
      if (lane < 16) wsum[lane] = w;
    }
    __syncthreads();
    int waveoff = (wave == 0) ? 0 : wsum[wave - 1];
    if (i < N) rowptr[i] = soff + waveoff + x - v;
    __syncthreads();
    if (tid == 0) soff += wsum[15];
    __syncthreads();
  }
  if (tid == 0) rowptr[N] = soff;
}

__global__ __launch_bounds__(256) void fill_kernel(const int* __restrict__ src,
                                                   const int* __restrict__ dst,
                                                   const int* __restrict__ rowptr,
                                                   int* __restrict__ cursor,
                                                   int* __restrict__ esrc, int E) {
  int e = blockIdx.x * blockDim.x + threadIdx.x;
  if (e < E) {
    int d = dst[e];
    int pos = atomicAdd(&cursor[d], 1);
    esrc[rowptr[d] + pos] = src[e];
  }
}

// ---------------- weight prep: transpose + hi/lo split ----------------
// Wt[col][k], k spans [Ws ; Wn] (K=512) for layers 0/1.

__global__ __launch_bounds__(256) void prep_w01_kernel(const float* __restrict__ Ws,
                                                       const float* __restrict__ Wn,
                                                       unsigned short* __restrict__ wh,
                                                       unsigned short* __restrict__ wl) {
  int idx = blockIdx.x * 256 + threadIdx.x;
  if (idx >= 256 * 512) return;
  int c = idx >> 9, k = idx & 511;
  float v = (k < 256) ? Ws[(size_t)k * 256 + c] : Wn[(size_t)(k - 256) * 256 + c];
  unsigned short h = f2bf(v);
  wh[idx] = h;
  wl[idx] = f2bf(v - bf2f(h));
}

// Layer 2: Wt[128][256]; cols 0-63 = Wn2 (t = h@Wn), cols 64-127 = Ws2 (p).
__global__ __launch_bounds__(256) void prep_w2_kernel(const float* __restrict__ Ws,
                                                      const float* __restrict__ Wn,
                                                      unsigned short* __restrict__ wh,
                                                      unsigned short* __restrict__ wl) {
  int idx = blockIdx.x * 256 + threadIdx.x;
  if (idx >= 128 * 256) return;
  int c = idx >> 8, k = idx & 255;
  float v = (c < 64) ? Wn[(size_t)k * 64 + c] : Ws[(size_t)k * 64 + (c - 64)];
  unsigned short h = f2bf(v);
  wh[idx] = h;
  wl[idx] = f2bf(v - bf2f(h));
}

// ---------------- aggregation (one wave/node, lane owns 4 features) ----------------

__global__ __launch_bounds__(256) void agg0_kernel(const float* __restrict__ h,
                                                   const int* __restrict__ rowptr,
                                                   const int* __restrict__ esrc,
                                                   unsigned short* __restrict__ ohi,
                                                   unsigned short* __restrict__ olo, int N) {
  int gid = blockIdx.x * blockDim.x + threadIdx.x;
  int node = gid >> 6;
  int lane = gid & 63;
  if (node >= N) return;
  int start = rowptr[node], end = rowptr[node + 1];
  const float* hb = h + (size_t)lane * 4;
  float4 acc = make_float4(0.f, 0.f, 0.f, 0.f);
  int e = start;
  for (; e + 8 <= end; e += 8) {
    float4 v[8];
#pragma unroll
    for (int u = 0; u < 8; ++u) v[u] = *(const float4*)(hb + (size_t)esrc[e + u] * 256);
#pragma unroll
    for (int u = 0; u < 8; ++u) {
      acc.x += v[u].x; acc.y += v[u].y; acc.z += v[u].z; acc.w += v[u].w;
    }
  }
  for (; e < end; ++e) {
    float4 v = *(const float4*)(hb + (size_t)esrc[e] * 256);
    acc.x += v.x; acc.y += v.y; acc.z += v.z; acc.w += v.w;
  }
  float inv = 1.0f / fmaxf((float)(end - start), 1.0f);
  float f[4] = {acc.x * inv, acc.y * inv, acc.z * inv, acc.w * inv};
  ushort4 hv, lv;
  unsigned short t;
  t = f2bf(f[0]); hv.x = t; lv.x = f2bf(f[0] - bf2f(t));
  t = f2bf(f[1]); hv.y = t; lv.y = f2bf(f[1] - bf2f(t));
  t = f2bf(f[2]); hv.z = t; lv.z = f2bf(f[2] - bf2f(t));
  t = f2bf(f[3]); hv.w = t; lv.w = f2bf(f[3] - bf2f(t));
  *(ushort4*)(ohi + (size_t)node * 256 + lane * 4) = hv;
  *(ushort4*)(olo + (size_t)node * 256 + lane * 4) = lv;
}

__global__ __launch_bounds__(256) void aggP_kernel(const unsigned short* __restrict__ ah,
                                                   const unsigned short* __restrict__ al,
                                                   const int* __restrict__ rowptr,
                                                   const int* __restrict__ esrc,
                                                   unsigned short* __restrict__ ohi,
                                                   unsigned short* __restrict__ olo, int N) {
  int gid = blockIdx.x * blockDim.x + threadIdx.x;
  int node = gid >> 6;
  int lane = gid & 63;
  if (node >= N) return;
  int start = rowptr[node], end = rowptr[node + 1];
  size_t lo4 = (size_t)lane * 4;
  float f[4] = {0.f, 0.f, 0.f, 0.f};
  int e = start;
  for (; e + 4 <= end; e += 4) {
    ushort4 va[4], vb[4];
#pragma unroll
    for (int u = 0; u < 4; ++u) {
      size_t ro = (size_t)esrc[e + u] * 256 + lo4;
      va[u] = *(const ushort4*)(ah + ro);
      vb[u] = *(const ushort4*)(al + ro);
    }
#pragma unroll
    for (int u = 0; u < 4; ++u) {
      f[0] += bf2f(va[u].x) + bf2f(vb[u].x);
      f[1] += bf2f(va[u].y) + bf2f(vb[u].y);
      f[2] += bf2f(va[u].z) + bf2f(vb[u].z);
      f[3] += bf2f(va[u].w) + bf2f(vb[u].w);
    }
  }
  for (; e < end; ++e) {
    size_t ro = (size_t)esrc[e] * 256 + lo4;
    ushort4 va = *(const ushort4*)(ah + ro);
    ushort4 vb = *(const ushort4*)(al + ro);
    f[0] += bf2f(va.x) + bf2f(vb.x);
    f[1] += bf2f(va.y) + bf2f(vb.y);
    f[2] += bf2f(va.z) + bf2f(vb.z);
    f[3] += bf2f(va.w) + bf2f(vb.w);
  }
  float inv = 1.0f / fmaxf((float)(end - start), 1.0f);
  ushort4 hv, lv;
  unsigned short t;
  f[0] *= inv; f[1] *= inv; f[2] *= inv; f[3] *= inv;
  t = f2bf(f[0]); hv.x = t; lv.x = f2bf(f[0] - bf2f(t));
  t = f2bf(f[1]); hv.y = t; lv.y = f2bf(f[1] - bf2f(t));
  t = f2bf(f[2]); hv.z = t; lv.z = f2bf(f[2] - bf2f(t));
  t = f2bf(f[3]); hv.w = t; lv.w = f2bf(f[3] - bf2f(t));
  *(ushort4*)(ohi + (size_t)node * 256 + lo4) = hv;
  *(ushort4*)(olo + (size_t)node * 256 + lo4) = lv;
}

// ---------------- split-bf16 MFMA GEMM ----------------
// out[M, NSW*64] = A[M, KT*32] @ Wt^T (+bias). BM=64, 4 waves; wave w owns
// cols w*NSW*16 .. +NSW*16-1. A staged fragment-contiguous in LDS via
// global_load_lds(16B); B fragments loaded straight to registers from
// Wt[col][k] planes. D = Ah*Bh + Ah*Bl + Al*Bh, fp32 accumulate.
// KT=16: A = [A1(256) | A2(256)] concat on K. EPI 0: relu->hi/lo planes.
// EPI 1: cols<64 -> Ot raw, cols>=64 -> Op + bias (layer-2 t/p trick).

template <int KT, int A1F32, int NSW, int EPI>
__global__ __launch_bounds__(256) void mfma_gemm_kernel(
    const float* __restrict__ A1f,
    const unsigned short* __restrict__ A1h, const unsigned short* __restrict__ A1l,
    const unsigned short* __restrict__ A2h, const unsigned short* __restrict__ A2l,
    const unsigned short* __restrict__ Wth, const unsigned short* __restrict__ Wtl,
    const float* __restrict__ bias,
    unsigned short* __restrict__ Oh, unsigned short* __restrict__ Ol,
    float* __restrict__ Ot, float* __restrict__ Op, int M) {
  __shared__ __align__(16) short As[2][4][512];  // [plane][m-subtile][lane*8] 8KB
  const int K = KT * 32;
  int tid = threadIdx.x;
  int w = tid >> 6, l = tid & 63;
  int l15 = l & 15, l4 = l >> 4;
  int m0 = blockIdx.x * 64;

  f32x4 acc[4][NSW] = {};

  for (int kt = 0; kt < KT; ++kt) {
    int khalf = (KT == 16 && kt >= 8) ? 1 : 0;
    int k0 = (kt - khalf * 8) * 32;  // offset within 256-wide plane
    const unsigned short* ph = khalf ? A2h : A1h;
    const unsigned short* pl = khalf ? A2l : A1l;

    // ---- stage A tile: wave w owns m-subtile ms = w, both planes ----
    {
      int ms = w;
      int row = m0 + ms * 16 + l15;
      if (row >= M) row = M - 1;  // clamped read; stores guarded in epilogue
      if (A1F32 && !khalf) {
        const float* gp = A1f + (size_t)row * 256 + k0 + l4 * 8;
        float4 v0 = *(const float4*)gp;
        float4 v1 = *(const float4*)(gp + 4);
        float f[8] = {v0.x, v0.y, v0.z, v0.w, v1.x, v1.y, v1.z, v1.w};
        short8 hi8, lo8;
#pragma unroll
        for (int j = 0; j < 8; ++j) {
          unsigned short h = f2bf(f[j]);
          hi8[j] = (short)h;
          lo8[j] = (short)f2bf(f[j] - bf2f(h));
        }
        *(short8*)&As[0][ms][l * 8] = hi8;
        *(short8*)&As[1][ms][l * 8] = lo8;
      } else {
        size_t ro = (size_t)row * 256 + k0 + l4 * 8;
        gload16(ph + ro, &As[0][ms][l * 8]);
        gload16(pl + ro, &As[1][ms][l * 8]);
      }
    }

    // ---- B fragments direct to registers ----
    short8 bh[NSW], bl[NSW];
#pragma unroll
    for (int ns = 0; ns < NSW; ++ns) {
      int col = w * (NSW * 16) + ns * 16 + l15;
      size_t o = (size_t)col * K + kt * 32 + l4 * 8;
      bh[ns] = *(const short8*)(Wth + o);
      bl[ns] = *(const short8*)(Wtl + o);
    }

    __syncthreads();  // drains global_load_lds + ds_writes; As visible

    short8 ah[4], al[4];
#pragma unroll
    for (int ms = 0; ms < 4; ++ms) {
      ah[ms] = *(const short8*)&As[0][ms][l * 8];
      al[ms] = *(const short8*)&As[1][ms][l * 8];
    }
#pragma unroll
    for (int ms = 0; ms < 4; ++ms)
#pragma unroll
      for (int ns = 0; ns < NSW; ++ns) {
        acc[ms][ns] = __builtin_amdgcn_mfma_f32_16x16x32_bf16(ah[ms], bh[ns], acc[ms][ns], 0, 0, 0);
        acc[ms][ns] = __builtin_amdgcn_mfma_f32_16x16x32_bf16(ah[ms], bl[ns], acc[ms][ns], 0, 0, 0);
        acc[ms][ns] = __builtin_amdgcn_mfma_f32_16x16x32_bf16(al[ms], bh[ns], acc[ms][ns], 0, 0, 0);
      }
    __syncthreads();  // reads done before next stage overwrites
  }

  // ---- epilogue: D[row=(l>>4)*4+i][col=l&15] per 16x16 fragment ----
  int rbase = m0 + l4 * 4;
#pragma unroll
  for (int ns = 0; ns < NSW; ++ns) {
    int col = w * (NSW * 16) + ns * 16 + l15;
    if (EPI == 0) {
      float bv = bias[col];
#pragma unroll
      for (int ms = 0; ms < 4; ++ms)
#pragma unroll
        for (int i = 0; i < 4; ++i) {
          int row = rbase + ms * 16 + i;
          if (row < M) {
            float x = fmaxf(acc[ms][ns][i] + bv, 0.f);
            unsigned short h = f2bf(x);
            Oh[(size_t)row * 256 + col] = h;
            Ol[(size_t)row * 256 + col] = f2bf(x - bf2f(h));
          }
        }
    } else {
#pragma unroll
      for (int ms = 0; ms < 4; ++ms)
#pragma unroll
        for (int i = 0; i < 4; ++i) {
          int row = rbase + ms * 16 + i;
          if (row < M) {
            if (col < 64) Ot[(size_t)row * 64 + col] = acc[ms][ns][i];
            else Op[(size_t)row * 64 + (col - 64)] = acc[ms][ns][i] + bias[col - 64];
          }
        }
    }
  }
}

// ------- fused agg(64-wide t) + p + log_softmax; one wave/node, lane=class -------

__global__ __launch_bounds__(256) void agg64_softmax_kernel(const float* __restrict__ t,
                                                            const float* __restrict__ p,
                                                            const int* __restrict__ rowptr,
                                                            const int* __restrict__ esrc,
                                                            float* __restrict__ out, int N) {
  int gid = blockIdx.x * blockDim.x + threadIdx.x;
  int node = gid >> 6;
  int lane = gid & 63;
  if (node >= N) return;
  int start = rowptr[node], end = rowptr[node + 1];
  float acc = 0.f;
  int e = start;
  for (; e + 8 <= end; e += 8) {
    float v[8];
#pragma unroll
    for (int u = 0; u < 8; ++u) v[u] = t[(size_t)esrc[e + u] * 64 + lane];
#pragma unroll
    for (int u = 0; u < 8; ++u) acc += v[u];
  }
  for (; e < end; ++e) acc += t[(size_t)esrc[e] * 64 + lane];
  float inv = 1.0f / fmaxf((float)(end - start), 1.0f);
  float x = p[(size_t)node * 64 + lane] + acc * inv;
  float m = x;
  for (int o = 32; o > 0; o >>= 1) m = fmaxf(m, __shfl_xor(m, o, 64));
  float ex = expf(x - m);
  float s = ex;
  for (int o = 32; o > 0; o >>= 1) s += __shfl_xor(s, o, 64);
  out[(size_t)node * 64 + lane] = x - m - logf(s);
}

// ---------------- launch ----------------

extern "C" void kernel_launch(void* const* d_in, const int* in_sizes, int n_in,
                              void* d_out, int out_size, void* d_ws, size_t ws_size,
                              hipStream_t stream) {
  const float* features = (const float*)d_in[0];
  const int* src = (const int*)d_in[1];
  const int* dst = (const int*)d_in[2];
  const float* Ws0 = (const float*)d_in[3];
  const float* Wn0 = (const float*)d_in[4];
  const float* b0  = (const float*)d_in[5];
  const float* Ws1 = (const float*)d_in[6];
  const float* Wn1 = (const float*)d_in[7];
  const float* b1  = (const float*)d_in[8];
  const float* Ws2 = (const float*)d_in[9];
  const float* Wn2 = (const float*)d_in[10];
  const float* b2  = (const float*)d_in[11];
  float* out = (float*)d_out;

  const int N = in_sizes[0] / 256;  // 50000
  const int E = in_sizes[1];        // 800000

  char* ws = (char*)d_ws;
  size_t off = 0;
  auto alloc = [&](size_t bytes) -> void* {
    void* p = ws + off;
    off += (bytes + 255) & ~(size_t)255;
    return p;
  };
  size_t planeB = (size_t)N * 256 * 2;  // 25.6 MB per bf16 plane
  unsigned short* hnh = (unsigned short*)alloc(planeB);
  unsigned short* hnl = (unsigned short*)alloc(planeB);
  unsigned short* h1h = (unsigned short*)alloc(planeB);
  unsigned short* h1l = (unsigned short*)alloc(planeB);
  unsigned short* h2h = (unsigned short*)alloc(planeB);
  unsigned short* h2l = (unsigned short*)alloc(planeB);
  unsigned short* wt0h = (unsigned short*)alloc(256 * 512 * 2);
  unsigned short* wt0l = (unsigned short*)alloc(256 * 512 * 2);
  unsigned short* wt1h = (unsigned short*)alloc(256 * 512 * 2);
  unsigned short* wt1l = (unsigned short*)alloc(256 * 512 * 2);
  unsigned short* wt2h = (unsigned short*)alloc(128 * 256 * 2);
  unsigned short* wt2l = (unsigned short*)alloc(128 * 256 * 2);
  int* rowptr = (int*)alloc((size_t)(N + 1) * 4);
  int* deg    = (int*)alloc((size_t)N * 4);
  int* cursor = (int*)alloc((size_t)N * 4);
  int* esrc   = (int*)alloc((size_t)E * 4);
  // t/p overlay h1 planes (h1 dead after layer-1 GEMM; 12.8MB each <= 25.6MB)
  float* t2 = (float*)h1h;
  float* p2 = (float*)h1l;
  (void)ws_size;

  hipMemsetAsync(deg, 0, (size_t)N * 4, stream);
  hipMemsetAsync(cursor, 0, (size_t)N * 4, stream);

  int eBlocks = (E + 255) / 256;
  count_deg_kernel<<<eBlocks, 256, 0, stream>>>(dst, deg, E);
  scan_kernel<<<1, 1024, 0, stream>>>(deg, rowptr, N);
  fill_kernel<<<eBlocks, 256, 0, stream>>>(src, dst, rowptr, cursor, esrc, E);

  prep_w01_kernel<<<512, 256, 0, stream>>>(Ws0, Wn0, wt0h, wt0l);
  prep_w01_kernel<<<512, 256, 0, stream>>>(Ws1, Wn1, wt1h, wt1l);
  prep_w2_kernel<<<128, 256, 0, stream>>>(Ws2, Wn2, wt2h, wt2l);

  int aggBlocks = ((size_t)N * 64 + 255) / 256;  // one wave per node
  int gemmBlocks = (N + 63) / 64;

  // layer 0: agg(features) -> hn planes; h1 = relu([feat|hn]@[Ws0;Wn0]+b0)
  agg0_kernel<<<aggBlocks, 256, 0, stream>>>(features, rowptr, esrc, hnh, hnl, N);
  mfma_gemm_kernel<16, 1, 4, 0><<<gemmBlocks, 256, 0, stream>>>(
      features, nullptr, nullptr, hnh, hnl, wt0h, wt0l, b0, h1h, h1l, nullptr, nullptr, N);
  // layer 1
  aggP_kernel<<<aggBlocks, 256, 0, stream>>>(h1h, h1l, rowptr, esrc, hnh, hnl, N);
  mfma_gemm_kernel<16, 0, 4, 0><<<gemmBlocks, 256, 0, stream>>>(
      nullptr, h1h, h1l, hnh, hnl, wt1h, wt1l, b1, h2h, h2l, nullptr, nullptr, N);
  // layer 2 (linearity): t = h2@Wn2, p = h2@Ws2+b2; out = logsoftmax(p + agg(t))
  mfma_gemm_kernel<8, 0, 2, 1><<<gemmBlocks, 256, 0, stream>>>(
      nullptr, h2h, h2l, nullptr, nullptr, wt2h, wt2l, b2, nullptr, nullptr, t2, p2, N);
  agg64_softmax_kernel<<<aggBlocks, 256, 0, stream>>>(t2, p2, rowptr, esrc, out, N);
}

// Round 11
// 732.096 us; speedup vs baseline: 1.4177x; 1.0061x over previous
//
#include <hip/hip_runtime.h>
#include <math.h>

// GraphSAGE 3-layer forward, MI355X. Split-bf16 (hi+lo) MFMA GEMMs with fp32
// accumulate (~fp32 accuracy), fp32 aggregation, CSR gather-sum.
// h tensors live as {hi,lo} bf16 plane pairs; weights pre-transposed/split.
// R8: agg kernels restructured for 16 in-flight row-gathers per wave
// (was 8); everything else identical to the round-7 PASS build.

typedef __attribute__((ext_vector_type(8))) short short8;
typedef __attribute__((ext_vector_type(4))) float f32x4;

__device__ __forceinline__ unsigned short f2bf(float x) {
  union { float f; unsigned int u; } c; c.f = x;
  unsigned int r = c.u + 0x7FFFu + ((c.u >> 16) & 1u);  // RNE
  return (unsigned short)(r >> 16);
}
__device__ __forceinline__ float bf2f(unsigned short h) {
  union { unsigned int u; float f; } c; c.u = ((unsigned int)h) << 16;
  return c.f;
}
__device__ __forceinline__ void gload16(const void* g, void* l) {
  void* gg = const_cast<void*>(g);
  __builtin_amdgcn_global_load_lds((__attribute__((address_space(1))) void*)gg,
                                   (__attribute__((address_space(3))) void*)l, 16, 0, 0);
}

// ---------------- CSR build ----------------

__global__ __launch_bounds__(256) void count_deg_kernel(const int* __restrict__ dst,
                                                        int* __restrict__ deg, int E) {
  int e = blockIdx.x * blockDim.x + threadIdx.x;
  if (e < E) atomicAdd(&deg[dst[e]], 1);
}

__global__ __launch_bounds__(1024) void scan_kernel(const int* __restrict__ deg,
                                                    int* __restrict__ rowptr, int N) {
  __shared__ int wsum[16];
  __shared__ int soff;
  int tid = threadIdx.x;
  int lane = tid & 63;
  int wave = tid >> 6;
  if (tid == 0) soff = 0;
  __syncthreads();
  for (int base = 0; base < N; base += 1024) {
    int i = base + tid;
    int v = (i < N) ? deg[i] : 0;
    int x = v;
#pragma unroll
    for (int d = 1; d < 64; d <<= 1) {
      int t = __shfl_up(x, d, 64);
      if (lane >= d) x += t;
    }
    if (lane == 63) wsum[wave] = x;
    __syncthreads();
    if (wave == 0) {
      int w = (lane < 16) ? wsum[lane] : 0;
#pragma unroll
      for (int d = 1; d < 16; d <<= 1) {
        int t = __shfl_up(w, d, 64);
        if (lane >= d) w += t;
      }
      if (lane < 16) wsum[lane] = w;
    }
    __syncthreads();
    int waveoff = (wave == 0) ? 0 : wsum[wave - 1];
    if (i < N) rowptr[i] = soff + waveoff + x - v;
    __syncthreads();
    if (tid == 0) soff += wsum[15];
    __syncthreads();
  }
  if (tid == 0) rowptr[N] = soff;
}

__global__ __launch_bounds__(256) void fill_kernel(const int* __restrict__ src,
                                                   const int* __restrict__ dst,
                                                   const int* __restrict__ rowptr,
                                                   int* __restrict__ cursor,
                                                   int* __restrict__ esrc, int E) {
  int e = blockIdx.x * blockDim.x + threadIdx.x;
  if (e < E) {
    int d = dst[e];
    int pos = atomicAdd(&cursor[d], 1);
    esrc[rowptr[d] + pos] = src[e];
  }
}

// ---------------- weight prep: transpose + hi/lo split ----------------
// Wt[col][k], k spans [Ws ; Wn] (K=512) for layers 0/1.

__global__ __launch_bounds__(256) void prep_w01_kernel(const float* __restrict__ Ws,
                                                       const float* __restrict__ Wn,
                                                       unsigned short* __restrict__ wh,
                                                       unsigned short* __restrict__ wl) {
  int idx = blockIdx.x * 256 + threadIdx.x;
  if (idx >= 256 * 512) return;
  int c = idx >> 9, k = idx & 511;
  float v = (k < 256) ? Ws[(size_t)k * 256 + c] : Wn[(size_t)(k - 256) * 256 + c];
  unsigned short h = f2bf(v);
  wh[idx] = h;
  wl[idx] = f2bf(v - bf2f(h));
}

// Layer 2: Wt[128][256]; cols 0-63 = Wn2 (t = h@Wn), cols 64-127 = Ws2 (p).
__global__ __launch_bounds__(256) void prep_w2_kernel(const float* __restrict__ Ws,
                                                      const float* __restrict__ Wn,
                                                      unsigned short* __restrict__ wh,
                                                      unsigned short* __restrict__ wl) {
  int idx = blockIdx.x * 256 + threadIdx.x;
  if (idx >= 128 * 256) return;
  int c = idx >> 8, k = idx & 255;
  float v = (c < 64) ? Wn[(size_t)k * 64 + c] : Ws[(size_t)k * 64 + (c - 64)];
  unsigned short h = f2bf(v);
  wh[idx] = h;
  wl[idx] = f2bf(v - bf2f(h));
}

// ---------------- aggregation (one wave/node, lane owns 4 features) ----------------
// R8: 16 row-gathers issued before first accumulate (2x in-flight vs r7).

__global__ __launch_bounds__(256) void agg0_kernel(const float* __restrict__ h,
                                                   const int* __restrict__ rowptr,
                                                   const int* __restrict__ esrc,
                                                   unsigned short* __restrict__ ohi,
                                                   unsigned short* __restrict__ olo, int N) {
  int gid = blockIdx.x * blockDim.x + threadIdx.x;
  int node = gid >> 6;
  int lane = gid & 63;
  if (node >= N) return;
  int start = rowptr[node], end = rowptr[node + 1];
  const float* hb = h + (size_t)lane * 4;
  float4 acc = make_float4(0.f, 0.f, 0.f, 0.f);
  int e = start;
  for (; e + 16 <= end; e += 16) {
    int s[16];
#pragma unroll
    for (int u = 0; u < 16; ++u) s[u] = esrc[e + u];
    float4 v[16];
#pragma unroll
    for (int u = 0; u < 16; ++u) v[u] = *(const float4*)(hb + (size_t)s[u] * 256);
#pragma unroll
    for (int u = 0; u < 16; ++u) {
      acc.x += v[u].x; acc.y += v[u].y; acc.z += v[u].z; acc.w += v[u].w;
    }
  }
  for (; e + 4 <= end; e += 4) {
    int s[4];
#pragma unroll
    for (int u = 0; u < 4; ++u) s[u] = esrc[e + u];
    float4 v[4];
#pragma unroll
    for (int u = 0; u < 4; ++u) v[u] = *(const float4*)(hb + (size_t)s[u] * 256);
#pragma unroll
    for (int u = 0; u < 4; ++u) {
      acc.x += v[u].x; acc.y += v[u].y; acc.z += v[u].z; acc.w += v[u].w;
    }
  }
  for (; e < end; ++e) {
    float4 v = *(const float4*)(hb + (size_t)esrc[e] * 256);
    acc.x += v.x; acc.y += v.y; acc.z += v.z; acc.w += v.w;
  }
  float inv = 1.0f / fmaxf((float)(end - start), 1.0f);
  float f[4] = {acc.x * inv, acc.y * inv, acc.z * inv, acc.w * inv};
  ushort4 hv, lv;
  unsigned short t;
  t = f2bf(f[0]); hv.x = t; lv.x = f2bf(f[0] - bf2f(t));
  t = f2bf(f[1]); hv.y = t; lv.y = f2bf(f[1] - bf2f(t));
  t = f2bf(f[2]); hv.z = t; lv.z = f2bf(f[2] - bf2f(t));
  t = f2bf(f[3]); hv.w = t; lv.w = f2bf(f[3] - bf2f(t));
  *(ushort4*)(ohi + (size_t)node * 256 + lane * 4) = hv;
  *(ushort4*)(olo + (size_t)node * 256 + lane * 4) = lv;
}

__global__ __launch_bounds__(256) void aggP_kernel(const unsigned short* __restrict__ ah,
                                                   const unsigned short* __restrict__ al,
                                                   const int* __restrict__ rowptr,
                                                   const int* __restrict__ esrc,
                                                   unsigned short* __restrict__ ohi,
                                                   unsigned short* __restrict__ olo, int N) {
  int gid = blockIdx.x * blockDim.x + threadIdx.x;
  int node = gid >> 6;
  int lane = gid & 63;
  if (node >= N) return;
  int start = rowptr[node], end = rowptr[node + 1];
  size_t lo4 = (size_t)lane * 4;
  float f[4] = {0.f, 0.f, 0.f, 0.f};
  int e = start;
  for (; e + 8 <= end; e += 8) {  // 8 rows x 2 planes = 16 loads in flight
    int s[8];
#pragma unroll
    for (int u = 0; u < 8; ++u) s[u] = esrc[e + u];
    ushort4 va[8], vb[8];
#pragma unroll
    for (int u = 0; u < 8; ++u) {
      size_t ro = (size_t)s[u] * 256 + lo4;
      va[u] = *(const ushort4*)(ah + ro);
      vb[u] = *(const ushort4*)(al + ro);
    }
#pragma unroll
    for (int u = 0; u < 8; ++u) {
      f[0] += bf2f(va[u].x) + bf2f(vb[u].x);
      f[1] += bf2f(va[u].y) + bf2f(vb[u].y);
      f[2] += bf2f(va[u].z) + bf2f(vb[u].z);
      f[3] += bf2f(va[u].w) + bf2f(vb[u].w);
    }
  }
  for (; e < end; ++e) {
    size_t ro = (size_t)esrc[e] * 256 + lo4;
    ushort4 va = *(const ushort4*)(ah + ro);
    ushort4 vb = *(const ushort4*)(al + ro);
    f[0] += bf2f(va.x) + bf2f(vb.x);
    f[1] += bf2f(va.y) + bf2f(vb.y);
    f[2] += bf2f(va.z) + bf2f(vb.z);
    f[3] += bf2f(va.w) + bf2f(vb.w);
  }
  float inv = 1.0f / fmaxf((float)(end - start), 1.0f);
  ushort4 hv, lv;
  unsigned short t;
  f[0] *= inv; f[1] *= inv; f[2] *= inv; f[3] *= inv;
  t = f2bf(f[0]); hv.x = t; lv.x = f2bf(f[0] - bf2f(t));
  t = f2bf(f[1]); hv.y = t; lv.y = f2bf(f[1] - bf2f(t));
  t = f2bf(f[2]); hv.z = t; lv.z = f2bf(f[2] - bf2f(t));
  t = f2bf(f[3]); hv.w = t; lv.w = f2bf(f[3] - bf2f(t));
  *(ushort4*)(ohi + (size_t)node * 256 + lo4) = hv;
  *(ushort4*)(olo + (size_t)node * 256 + lo4) = lv;
}

// ---------------- split-bf16 MFMA GEMM ----------------
// out[M, NSW*64] = A[M, KT*32] @ Wt^T (+bias). BM=64, 4 waves; wave w owns
// cols w*NSW*16 .. +NSW*16-1. A staged fragment-contiguous in LDS via
// global_load_lds(16B); B fragments loaded straight to registers from
// Wt[col][k] planes. D = Ah*Bh + Ah*Bl + Al*Bh, fp32 accumulate.
// KT=16: A = [A1(256) | A2(256)] concat on K. EPI 0: relu->hi/lo planes.
// EPI 1: cols<64 -> Ot raw, cols>=64 -> Op + bias (layer-2 t/p trick).

template <int KT, int A1F32, int NSW, int EPI>
__global__ __launch_bounds__(256) void mfma_gemm_kernel(
    const float* __restrict__ A1f,
    const unsigned short* __restrict__ A1h, const unsigned short* __restrict__ A1l,
    const unsigned short* __restrict__ A2h, const unsigned short* __restrict__ A2l,
    const unsigned short* __restrict__ Wth, const unsigned short* __restrict__ Wtl,
    const float* __restrict__ bias,
    unsigned short* __restrict__ Oh, unsigned short* __restrict__ Ol,
    float* __restrict__ Ot, float* __restrict__ Op, int M) {
  __shared__ __align__(16) short As[2][4][512];  // [plane][m-subtile][lane*8] 8KB
  const int K = KT * 32;
  int tid = threadIdx.x;
  int w = tid >> 6, l = tid & 63;
  int l15 = l & 15, l4 = l >> 4;
  int m0 = blockIdx.x * 64;

  f32x4 acc[4][NSW] = {};

  for (int kt = 0; kt < KT; ++kt) {
    int khalf = (KT == 16 && kt >= 8) ? 1 : 0;
    int k0 = (kt - khalf * 8) * 32;  // offset within 256-wide plane
    const unsigned short* ph = khalf ? A2h : A1h;
    const unsigned short* pl = khalf ? A2l : A1l;

    // ---- stage A tile: wave w owns m-subtile ms = w, both planes ----
    {
      int ms = w;
      int row = m0 + ms * 16 + l15;
      if (row >= M) row = M - 1;  // clamped read; stores guarded in epilogue
      if (A1F32 && !khalf) {
        const float* gp = A1f + (size_t)row * 256 + k0 + l4 * 8;
        float4 v0 = *(const float4*)gp;
        float4 v1 = *(const float4*)(gp + 4);
        float f[8] = {v0.x, v0.y, v0.z, v0.w, v1.x, v1.y, v1.z, v1.w};
        short8 hi8, lo8;
#pragma unroll
        for (int j = 0; j < 8; ++j) {
          unsigned short h = f2bf(f[j]);
          hi8[j] = (short)h;
          lo8[j] = (short)f2bf(f[j] - bf2f(h));
        }
        *(short8*)&As[0][ms][l * 8] = hi8;
        *(short8*)&As[1][ms][l * 8] = lo8;
      } else {
        size_t ro = (size_t)row * 256 + k0 + l4 * 8;
        gload16(ph + ro, &As[0][ms][l * 8]);
        gload16(pl + ro, &As[1][ms][l * 8]);
      }
    }

    // ---- B fragments direct to registers ----
    short8 bh[NSW], bl[NSW];
#pragma unroll
    for (int ns = 0; ns < NSW; ++ns) {
      int col = w * (NSW * 16) + ns * 16 + l15;
      size_t o = (size_t)col * K + kt * 32 + l4 * 8;
      bh[ns] = *(const short8*)(Wth + o);
      bl[ns] = *(const short8*)(Wtl + o);
    }

    __syncthreads();  // drains global_load_lds + ds_writes; As visible

    short8 ah[4], al[4];
#pragma unroll
    for (int ms = 0; ms < 4; ++ms) {
      ah[ms] = *(const short8*)&As[0][ms][l * 8];
      al[ms] = *(const short8*)&As[1][ms][l * 8];
    }
#pragma unroll
    for (int ms = 0; ms < 4; ++ms)
#pragma unroll
      for (int ns = 0; ns < NSW; ++ns) {
        acc[ms][ns] = __builtin_amdgcn_mfma_f32_16x16x32_bf16(ah[ms], bh[ns], acc[ms][ns], 0, 0, 0);
        acc[ms][ns] = __builtin_amdgcn_mfma_f32_16x16x32_bf16(ah[ms], bl[ns], acc[ms][ns], 0, 0, 0);
        acc[ms][ns] = __builtin_amdgcn_mfma_f32_16x16x32_bf16(al[ms], bh[ns], acc[ms][ns], 0, 0, 0);
      }
    __syncthreads();  // reads done before next stage overwrites
  }

  // ---- epilogue: D[row=(l>>4)*4+i][col=l&15] per 16x16 fragment ----
  int rbase = m0 + l4 * 4;
#pragma unroll
  for (int ns = 0; ns < NSW; ++ns) {
    int col = w * (NSW * 16) + ns * 16 + l15;
    if (EPI == 0) {
      float bv = bias[col];
#pragma unroll
      for (int ms = 0; ms < 4; ++ms)
#pragma unroll
        for (int i = 0; i < 4; ++i) {
          int row = rbase + ms * 16 + i;
          if (row < M) {
            float x = fmaxf(acc[ms][ns][i] + bv, 0.f);
            unsigned short h = f2bf(x);
            Oh[(size_t)row * 256 + col] = h;
            Ol[(size_t)row * 256 + col] = f2bf(x - bf2f(h));
          }
        }
    } else {
#pragma unroll
      for (int ms = 0; ms < 4; ++ms)
#pragma unroll
        for (int i = 0; i < 4; ++i) {
          int row = rbase + ms * 16 + i;
          if (row < M) {
            if (col < 64) Ot[(size_t)row * 64 + col] = acc[ms][ns][i];
            else Op[(size_t)row * 64 + (col - 64)] = acc[ms][ns][i] + bias[col - 64];
          }
        }
    }
  }
}

// ------- fused agg(64-wide t) + p + log_softmax; one wave/node, lane=class -------

__global__ __launch_bounds__(256) void agg64_softmax_kernel(const float* __restrict__ t,
                                                            const float* __restrict__ p,
                                                            const int* __restrict__ rowptr,
                                                            const int* __restrict__ esrc,
                                                            float* __restrict__ out, int N) {
  int gid = blockIdx.x * blockDim.x + threadIdx.x;
  int node = gid >> 6;
  int lane = gid & 63;
  if (node >= N) return;
  int start = rowptr[node], end = rowptr[node + 1];
  float acc = 0.f;
  int e = start;
  for (; e + 16 <= end; e += 16) {
    int s[16];
#pragma unroll
    for (int u = 0; u < 16; ++u) s[u] = esrc[e + u];
    float v[16];
#pragma unroll
    for (int u = 0; u < 16; ++u) v[u] = t[(size_t)s[u] * 64 + lane];
#pragma unroll
    for (int u = 0; u < 16; ++u) acc += v[u];
  }
  for (; e + 4 <= end; e += 4) {
    int s[4];
#pragma unroll
    for (int u = 0; u < 4; ++u) s[u] = esrc[e + u];
    float v[4];
#pragma unroll
    for (int u = 0; u < 4; ++u) v[u] = t[(size_t)s[u] * 64 + lane];
#pragma unroll
    for (int u = 0; u < 4; ++u) acc += v[u];
  }
  for (; e < end; ++e) acc += t[(size_t)esrc[e] * 64 + lane];
  float inv = 1.0f / fmaxf((float)(end - start), 1.0f);
  float x = p[(size_t)node * 64 + lane] + acc * inv;
  float m = x;
  for (int o = 32; o > 0; o >>= 1) m = fmaxf(m, __shfl_xor(m, o, 64));
  float ex = expf(x - m);
  float s = ex;
  for (int o = 32; o > 0; o >>= 1) s += __shfl_xor(s, o, 64);
  out[(size_t)node * 64 + lane] = x - m - logf(s);
}

// ---------------- launch ----------------

extern "C" void kernel_launch(void* const* d_in, const int* in_sizes, int n_in,
                              void* d_out, int out_size, void* d_ws, size_t ws_size,
                              hipStream_t stream) {
  const float* features = (const float*)d_in[0];
  const int* src = (const int*)d_in[1];
  const int* dst = (const int*)d_in[2];
  const float* Ws0 = (const float*)d_in[3];
  const float* Wn0 = (const float*)d_in[4];
  const float* b0  = (const float*)d_in[5];
  const float* Ws1 = (const float*)d_in[6];
  const float* Wn1 = (const float*)d_in[7];
  const float* b1  = (const float*)d_in[8];
  const float* Ws2 = (const float*)d_in[9];
  const float* Wn2 = (const float*)d_in[10];
  const float* b2  = (const float*)d_in[11];
  float* out = (float*)d_out;

  const int N = in_sizes[0] / 256;  // 50000
  const int E = in_sizes[1];        // 800000

  char* ws = (char*)d_ws;
  size_t off = 0;
  auto alloc = [&](size_t bytes) -> void* {
    void* p = ws + off;
    off += (bytes + 255) & ~(size_t)255;
    return p;
  };
  size_t planeB = (size_t)N * 256 * 2;  // 25.6 MB per bf16 plane
  unsigned short* hnh = (unsigned short*)alloc(planeB);
  unsigned short* hnl = (unsigned short*)alloc(planeB);
  unsigned short* h1h = (unsigned short*)alloc(planeB);
  unsigned short* h1l = (unsigned short*)alloc(planeB);
  unsigned short* h2h = (unsigned short*)alloc(planeB);
  unsigned short* h2l = (unsigned short*)alloc(planeB);
  unsigned short* wt0h = (unsigned short*)alloc(256 * 512 * 2);
  unsigned short* wt0l = (unsigned short*)alloc(256 * 512 * 2);
  unsigned short* wt1h = (unsigned short*)alloc(256 * 512 * 2);
  unsigned short* wt1l = (unsigned short*)alloc(256 * 512 * 2);
  unsigned short* wt2h = (unsigned short*)alloc(128 * 256 * 2);
  unsigned short* wt2l = (unsigned short*)alloc(128 * 256 * 2);
  int* rowptr = (int*)alloc((size_t)(N + 1) * 4);
  int* deg    = (int*)alloc((size_t)N * 4);
  int* cursor = (int*)alloc((size_t)N * 4);
  int* esrc   = (int*)alloc((size_t)E * 4);
  // t/p overlay h1 planes (h1 dead after layer-1 GEMM; 12.8MB each <= 25.6MB)
  float* t2 = (float*)h1h;
  float* p2 = (float*)h1l;
  (void)ws_size;

  hipMemsetAsync(deg, 0, (size_t)N * 4, stream);
  hipMemsetAsync(cursor, 0, (size_t)N * 4, stream);

  int eBlocks = (E + 255) / 256;
  count_deg_kernel<<<eBlocks, 256, 0, stream>>>(dst, deg, E);
  scan_kernel<<<1, 1024, 0, stream>>>(deg, rowptr, N);
  fill_kernel<<<eBlocks, 256, 0, stream>>>(src, dst, rowptr, cursor, esrc, E);

  prep_w01_kernel<<<512, 256, 0, stream>>>(Ws0, Wn0, wt0h, wt0l);
  prep_w01_kernel<<<512, 256, 0, stream>>>(Ws1, Wn1, wt1h, wt1l);
  prep_w2_kernel<<<128, 256, 0, stream>>>(Ws2, Wn2, wt2h, wt2l);

  int aggBlocks = ((size_t)N * 64 + 255) / 256;  // one wave per node
  int gemmBlocks = (N + 63) / 64;

  // layer 0: agg(features) -> hn planes; h1 = relu([feat|hn]@[Ws0;Wn0]+b0)
  agg0_kernel<<<aggBlocks, 256, 0, stream>>>(features, rowptr, esrc, hnh, hnl, N);
  mfma_gemm_kernel<16, 1, 4, 0><<<gemmBlocks, 256, 0, stream>>>(
      features, nullptr, nullptr, hnh, hnl, wt0h, wt0l, b0, h1h, h1l, nullptr, nullptr, N);
  // layer 1
  aggP_kernel<<<aggBlocks, 256, 0, stream>>>(h1h, h1l, rowptr, esrc, hnh, hnl, N);
  mfma_gemm_kernel<16, 0, 4, 0><<<gemmBlocks, 256, 0, stream>>>(
      nullptr, h1h, h1l, hnh, hnl, wt1h, wt1l, b1, h2h, h2l, nullptr, nullptr, N);
  // layer 2 (linearity): t = h2@Wn2, p = h2@Ws2+b2; out = logsoftmax(p + agg(t))
  mfma_gemm_kernel<8, 0, 2, 1><<<gemmBlocks, 256, 0, stream>>>(
      nullptr, h2h, h2l, nullptr, nullptr, wt2h, wt2l, b2, nullptr, nullptr, t2, p2, N);
  agg64_softmax_kernel<<<aggBlocks, 256, 0, stream>>>(t2, p2, rowptr, esrc, out, N);
}